// Round 3
// baseline (1256.208 us; speedup 1.0000x reference)
//
#include <hip/hip_runtime.h>
#include <stdint.h>

typedef __bf16 bf16_t;
using bf16x8 = __attribute__((ext_vector_type(8))) __bf16;
using f32x4  = __attribute__((ext_vector_type(4))) float;

#define DEVINL __device__ __forceinline__

DEVINL void gload_lds16(const bf16_t* g, char* l) {
  __builtin_amdgcn_global_load_lds(
      (const __attribute__((address_space(1))) void*)g,
      (__attribute__((address_space(3))) void*)l, 16, 0, 0);
}

// ---------------- weight convert: w[K][N] fp32 -> wt[N][K] bf16 ----------------
__global__ void conv_w(const float* __restrict__ w, bf16_t* __restrict__ wt,
                       int kshift, int N, int total) {
  int i = blockIdx.x * 256 + threadIdx.x;
  if (i >= total) return;
  int n = i >> kshift, k = i & ((1 << kshift) - 1);
  wt[i] = (bf16_t)w[(size_t)k * N + n];
}

// ---------------- relative position bias table: tab[h][n][m] ----------------
__global__ void build_bias(const float* __restrict__ rpb, float* __restrict__ tab) {
  int idx = blockIdx.x * 256 + threadIdx.x;   // 16384 = 128*128
  int n = idx >> 7, m = idx & 127;
  int it1 = n >> 6, ih1 = (n >> 3) & 7, iw1 = n & 7;
  int it2 = m >> 6, ih2 = (m >> 3) & 7, iw2 = m & 7;
  int ridx = (it1 - it2 + 1) * 225 + (ih1 - ih2 + 7) * 15 + (iw1 - iw2 + 7);
#pragma unroll
  for (int h = 0; h < 8; ++h)
    tab[(h << 14) + idx] = rpb[ridx * 8 + h];
}

// ---------------- layernorm: fp32 [M,256] -> bf16 [M,256] ----------------
__global__ __launch_bounds__(256)
void ln_kernel(const float* __restrict__ x, const float* __restrict__ g,
               const float* __restrict__ b, bf16_t* __restrict__ out) {
  int row = blockIdx.x * 4 + (threadIdx.x >> 6);
  int lane = threadIdx.x & 63;
  float4 v = *((const float4*)(x + (size_t)row * 256) + lane);
  float s = v.x + v.y + v.z + v.w;
#pragma unroll
  for (int m = 1; m < 64; m <<= 1) s += __shfl_xor(s, m);
  float mean = s * 0.00390625f;
  float dx = v.x - mean, dy = v.y - mean, dz = v.z - mean, dw = v.w - mean;
  float s2 = dx * dx + dy * dy + dz * dz + dw * dw;
#pragma unroll
  for (int m = 1; m < 64; m <<= 1) s2 += __shfl_xor(s2, m);
  float rstd = rsqrtf(s2 * 0.00390625f + 1e-5f);
  float4 gv = *((const float4*)g + lane);
  float4 bv = *((const float4*)b + lane);
  union { bf16_t h[4]; uint2 u; } pk;
  pk.h[0] = (bf16_t)(dx * rstd * gv.x + bv.x);
  pk.h[1] = (bf16_t)(dy * rstd * gv.y + bv.y);
  pk.h[2] = (bf16_t)(dz * rstd * gv.z + bv.z);
  pk.h[3] = (bf16_t)(dw * rstd * gv.w + bv.w);
  *(uint2*)(out + (size_t)row * 256 + lane * 4) = pk.u;
}

// ---------------- GEMM: C = A[M,K](bf16) @ Bt[N,K]^T + bias ----------------
// EPI 0: bf16 out, cols<qcols scaled by qscale (qkv)
// EPI 1: fp32 out = resid + val (proj / mlp2, residual add)
// EPI 2: bf16 out = gelu(val)   (mlp1)
template <int EPI>
__global__ __launch_bounds__(256, 2)
void gemm_bt(const bf16_t* __restrict__ A, const bf16_t* __restrict__ Bt,
             const float* __restrict__ bias, const float* __restrict__ resid,
             void* __restrict__ outp, int M, int N, int K, float qscale, int qcols) {
  __shared__ __align__(16) char ldsA[16384];   // 128 rows x 64 k x bf16, swizzled
  __shared__ __align__(16) char ldsB[16384];
  const int tid = threadIdx.x;
  const int lane = tid & 63, wid = tid >> 6;
  const int l15 = lane & 15, l4 = lane >> 4;
  const int tn = blockIdx.x, tm = blockIdx.y;
  const int wm = wid >> 1, wn = wid & 1;

  f32x4 acc[4][4] = {};
  const int nK = K >> 6;
  const size_t arow0 = (size_t)(tm * 128) * K;

  for (int kt = 0; kt < nK; ++kt) {
    const int kb = kt * 64;
#pragma unroll
    for (int i = 0; i < 4; ++i) {
      int c = i * 256 + tid;
      int row = c >> 3, slot = c & 7;
      int ss = slot ^ (row & 7);
      gload_lds16(A + arow0 + (size_t)row * K + kb + ss * 8,
                  ldsA + (i * 256 + wid * 64) * 16);
      gload_lds16(Bt + (size_t)(tn * 128 + row) * K + kb + ss * 8,
                  ldsB + (i * 256 + wid * 64) * 16);
    }
    __syncthreads();
    bf16x8 af[4][2], bfr[4][2];
#pragma unroll
    for (int mi = 0; mi < 4; ++mi) {
      int row = wm * 64 + mi * 16 + l15;
      int sw = (row & 7) << 4;
#pragma unroll
      for (int kk = 0; kk < 2; ++kk)
        af[mi][kk] = *(const bf16x8*)(ldsA + row * 128 + ((kk * 64 + l4 * 16) ^ sw));
    }
#pragma unroll
    for (int ni = 0; ni < 4; ++ni) {
      int row = wn * 64 + ni * 16 + l15;
      int sw = (row & 7) << 4;
#pragma unroll
      for (int kk = 0; kk < 2; ++kk)
        bfr[ni][kk] = *(const bf16x8*)(ldsB + row * 128 + ((kk * 64 + l4 * 16) ^ sw));
    }
#pragma unroll
    for (int kk = 0; kk < 2; ++kk)
#pragma unroll
      for (int mi = 0; mi < 4; ++mi)
#pragma unroll
        for (int ni = 0; ni < 4; ++ni)
          acc[mi][ni] = __builtin_amdgcn_mfma_f32_16x16x32_bf16(
              af[mi][kk], bfr[ni][kk], acc[mi][ni], 0, 0, 0);
    __syncthreads();
  }

#pragma unroll
  for (int mi = 0; mi < 4; ++mi) {
#pragma unroll
    for (int ni = 0; ni < 4; ++ni) {
      int col = tn * 128 + wn * 64 + ni * 16 + l15;
      float bv = bias[col];
#pragma unroll
      for (int v = 0; v < 4; ++v) {
        int row = tm * 128 + wm * 64 + mi * 16 + l4 * 4 + v;
        float val = acc[mi][ni][v] + bv;
        size_t idx = (size_t)row * N + col;
        if constexpr (EPI == 0) {
          if (col < qcols) val *= qscale;
          ((bf16_t*)outp)[idx] = (bf16_t)val;
        } else if constexpr (EPI == 1) {
          ((float*)outp)[idx] = resid[idx] + val;
        } else {
          ((bf16_t*)outp)[idx] =
              (bf16_t)(0.5f * val * (1.0f + erff(val * 0.7071067811865475f)));
        }
      }
    }
  }
}

// ---------------- windowed attention: 1 block per (window, head) ----------------
template <bool SHIFTED>
__global__ __launch_bounds__(256, 2)
void attn_kernel(const bf16_t* __restrict__ qkv, const float* __restrict__ btab,
                 bf16_t* __restrict__ o) {
  __shared__ int tok_s[128];
  __shared__ int rid_s[128];
  __shared__ __align__(16) char VtL[8192];    // V^T [32 d][128 tok] bf16, swizzled
  __shared__ __align__(16) char PL[32768];    // P [128][128] bf16, swizzled

  const int tid = threadIdx.x, lane = tid & 63, wid = tid >> 6;
  const int l15 = lane & 15, l4 = lane >> 4;
  const int blk = blockIdx.x;
  const int head = blk & 7;
  const int win = blk >> 3;
  const int b = win >> 8, rem = win & 255;
  const int tw = rem >> 6, hw = (rem >> 3) & 7, ww = rem & 7;

  if (tid < 128) {
    int it = tid >> 6, ih = (tid >> 3) & 7, iw = tid & 7;
    int pt = tw * 2 + it, ph = hw * 8 + ih, pw = ww * 8 + iw;
    int t = pt, h = ph, w = pw;
    if (SHIFTED) {
      t = (pt + 1) & 7; h = (ph + 4) & 63; w = (pw + 4) & 63;
      int rt = pt < 6 ? 0 : (pt < 7 ? 1 : 2);
      int rh = ph < 56 ? 0 : (ph < 60 ? 1 : 2);
      int rw2 = pw < 56 ? 0 : (pw < 60 ? 1 : 2);
      rid_s[tid] = rt * 9 + rh * 3 + rw2;
    }
    tok_s[tid] = ((b * 8 + t) << 12) + (h << 6) + w;
  }
  __syncthreads();

  const int hoff = head << 5;
  // stage V transposed (swizzled)
#pragma unroll
  for (int i = 0; i < 2; ++i) {
    int c = i * 256 + tid;
    int tok = c >> 2, dc = c & 3;
    bf16x8 vv = *(const bf16x8*)(qkv + (size_t)tok_s[tok] * 768 + 512 + hoff + dc * 8);
#pragma unroll
    for (int j = 0; j < 8; ++j) {
      int d = dc * 8 + j;
      *(bf16_t*)(VtL + d * 256 + ((tok * 2) ^ ((d & 7) << 4))) = vv[j];
    }
  }

  // Q/K fragments directly from global (64B-aligned slices)
  bf16x8 qf[2], kf[8];
#pragma unroll
  for (int mi = 0; mi < 2; ++mi) {
    int tok = tok_s[wid * 32 + mi * 16 + l15];
    qf[mi] = *(const bf16x8*)(qkv + (size_t)tok * 768 + hoff + l4 * 8);
  }
#pragma unroll
  for (int ni = 0; ni < 8; ++ni) {
    int tok = tok_s[ni * 16 + l15];
    kf[ni] = *(const bf16x8*)(qkv + (size_t)tok * 768 + 256 + hoff + l4 * 8);
  }
  const f32x4 zz = {0.f, 0.f, 0.f, 0.f};
  f32x4 s[2][8];
#pragma unroll
  for (int mi = 0; mi < 2; ++mi)
#pragma unroll
    for (int ni = 0; ni < 8; ++ni)
      s[mi][ni] = __builtin_amdgcn_mfma_f32_16x16x32_bf16(qf[mi], kf[ni], zz, 0, 0, 0);

  // bias + mask + softmax (fp32) + write P (bf16, swizzled)
  const float* bt = btab + (head << 14);
#pragma unroll
  for (int mi = 0; mi < 2; ++mi) {
#pragma unroll
    for (int v = 0; v < 4; ++v) {
      int row = wid * 32 + mi * 16 + l4 * 4 + v;
      float mx = -1e30f;
#pragma unroll
      for (int ni = 0; ni < 8; ++ni) {
        int col = ni * 16 + l15;
        float xx = s[mi][ni][v] + bt[(row << 7) + col];
        if (SHIFTED) { if (rid_s[row] != rid_s[col]) xx -= 100.f; }
        s[mi][ni][v] = xx;
        mx = fmaxf(mx, xx);
      }
#pragma unroll
      for (int d = 1; d < 16; d <<= 1) mx = fmaxf(mx, __shfl_xor(mx, d));
      float sum = 0.f;
#pragma unroll
      for (int ni = 0; ni < 8; ++ni) {
        float e = __expf(s[mi][ni][v] - mx);
        s[mi][ni][v] = e;
        sum += e;
      }
#pragma unroll
      for (int d = 1; d < 16; d <<= 1) sum += __shfl_xor(sum, d);
      float inv = 1.0f / sum;
      int sw = (row & 7) << 4;
#pragma unroll
      for (int ni = 0; ni < 8; ++ni) {
        int col = ni * 16 + l15;
        *(bf16_t*)(PL + row * 256 + ((col * 2) ^ sw)) = (bf16_t)(s[mi][ni][v] * inv);
      }
    }
  }
  __syncthreads();

  // O = P @ V
  f32x4 oacc[2][2] = {};
#pragma unroll
  for (int kk = 0; kk < 4; ++kk) {
    bf16x8 pf[2], vf[2];
#pragma unroll
    for (int mi = 0; mi < 2; ++mi) {
      int row = wid * 32 + mi * 16 + l15;
      pf[mi] = *(const bf16x8*)(PL + row * 256 + ((kk * 64 + l4 * 16) ^ ((row & 7) << 4)));
    }
#pragma unroll
    for (int nj = 0; nj < 2; ++nj) {
      int d = nj * 16 + l15;
      vf[nj] = *(const bf16x8*)(VtL + d * 256 + ((kk * 64 + l4 * 16) ^ ((d & 7) << 4)));
    }
#pragma unroll
    for (int mi = 0; mi < 2; ++mi)
#pragma unroll
      for (int nj = 0; nj < 2; ++nj)
        oacc[mi][nj] = __builtin_amdgcn_mfma_f32_16x16x32_bf16(pf[mi], vf[nj], oacc[mi][nj], 0, 0, 0);
  }
#pragma unroll
  for (int mi = 0; mi < 2; ++mi)
#pragma unroll
    for (int v = 0; v < 4; ++v) {
      int tok = tok_s[wid * 32 + mi * 16 + l4 * 4 + v];
#pragma unroll
      for (int nj = 0; nj < 2; ++nj) {
        int col = nj * 16 + l15;
        o[(size_t)tok * 256 + hoff + col] = (bf16_t)(oacc[mi][nj][v]);
      }
    }
}

// ---------------- launch ----------------
extern "C" void kernel_launch(void* const* d_in, const int* in_sizes, int n_in,
                              void* d_out, int out_size, void* d_ws, size_t ws_size,
                              hipStream_t stream) {
  const float* x       = (const float*)d_in[0];
  const float* rpb1    = (const float*)d_in[1];
  const float* qkv_w1  = (const float*)d_in[2];
  const float* qkv_b1  = (const float*)d_in[3];
  const float* proj_w1 = (const float*)d_in[4];
  const float* proj_b1 = (const float*)d_in[5];
  const float* rpb2    = (const float*)d_in[6];
  const float* qkv_w2  = (const float*)d_in[7];
  const float* qkv_b2  = (const float*)d_in[8];
  const float* proj_w2 = (const float*)d_in[9];
  const float* proj_b2 = (const float*)d_in[10];
  const float* g1  = (const float*)d_in[11];
  const float* be1 = (const float*)d_in[12];
  const float* g2  = (const float*)d_in[13];
  const float* be2 = (const float*)d_in[14];
  const float* g3  = (const float*)d_in[15];
  const float* be3 = (const float*)d_in[16];
  const float* g4  = (const float*)d_in[17];
  const float* be4 = (const float*)d_in[18];
  const float* m1w1 = (const float*)d_in[19];
  const float* m1b1 = (const float*)d_in[20];
  const float* m1w2 = (const float*)d_in[21];
  const float* m1b2 = (const float*)d_in[22];
  const float* m2w1 = (const float*)d_in[23];
  const float* m2b1 = (const float*)d_in[24];
  const float* m2w2 = (const float*)d_in[25];
  const float* m2b2 = (const float*)d_in[26];
  float* out = (float*)d_out;

  char* ws = (char*)d_ws;
  bf16_t* qkvb = (bf16_t*)ws;                       // 192 MB (reused as MLP hidden)
  bf16_t* xn   = (bf16_t*)(ws + 201326592ull);      // 64 MB (ln out, reused as attn out)
  bf16_t* wts  = (bf16_t*)(ws + 268435456ull);      // 2 MB bf16 weights (transposed)
  float* btab1 = (float*)(ws + 270532608ull);       // 512 KB
  float* btab2 = btab1 + 131072;                    // 512 KB

  bf16_t* qw1t = wts;
  bf16_t* pw1t = wts + 196608;
  bf16_t* a1t  = wts + 262144;
  bf16_t* a2t  = wts + 393216;
  bf16_t* qw2t = wts + 524288;
  bf16_t* pw2t = wts + 720896;
  bf16_t* c1t  = wts + 786432;
  bf16_t* c2t  = wts + 917504;

  conv_w<<<768, 256, 0, stream>>>(qkv_w1, qw1t, 8, 768, 196608);
  conv_w<<<256, 256, 0, stream>>>(proj_w1, pw1t, 8, 256, 65536);
  conv_w<<<512, 256, 0, stream>>>(m1w1, a1t, 8, 512, 131072);
  conv_w<<<512, 256, 0, stream>>>(m1w2, a2t, 9, 256, 131072);
  conv_w<<<768, 256, 0, stream>>>(qkv_w2, qw2t, 8, 768, 196608);
  conv_w<<<256, 256, 0, stream>>>(proj_w2, pw2t, 8, 256, 65536);
  conv_w<<<512, 256, 0, stream>>>(m2w1, c1t, 8, 512, 131072);
  conv_w<<<512, 256, 0, stream>>>(m2w2, c2t, 9, 256, 131072);
  build_bias<<<64, 256, 0, stream>>>(rpb1, btab1);
  build_bias<<<64, 256, 0, stream>>>(rpb2, btab2);

  const float SC = 0.17677669529663687f;  // 32^-0.5
  const int M = 131072;

  // ---- block 1 (no shift) ----
  ln_kernel<<<32768, 256, 0, stream>>>(x, g1, be1, xn);
  gemm_bt<0><<<dim3(6, 1024), 256, 0, stream>>>(xn, qw1t, qkv_b1, nullptr, qkvb, M, 768, 256, SC, 256);
  attn_kernel<false><<<8192, 256, 0, stream>>>(qkvb, btab1, xn);
  gemm_bt<1><<<dim3(2, 1024), 256, 0, stream>>>(xn, pw1t, proj_b1, x, out, M, 256, 256, 1.f, 0);
  ln_kernel<<<32768, 256, 0, stream>>>(out, g2, be2, xn);
  gemm_bt<2><<<dim3(4, 1024), 256, 0, stream>>>(xn, a1t, m1b1, nullptr, qkvb, M, 512, 256, 1.f, 0);
  gemm_bt<1><<<dim3(2, 1024), 256, 0, stream>>>(qkvb, a2t, m1b2, out, out, M, 256, 512, 1.f, 0);

  // ---- block 2 (shifted, masked) ----
  ln_kernel<<<32768, 256, 0, stream>>>(out, g3, be3, xn);
  gemm_bt<0><<<dim3(6, 1024), 256, 0, stream>>>(xn, qw2t, qkv_b2, nullptr, qkvb, M, 768, 256, SC, 256);
  attn_kernel<true><<<8192, 256, 0, stream>>>(qkvb, btab2, xn);
  gemm_bt<1><<<dim3(2, 1024), 256, 0, stream>>>(xn, pw2t, proj_b2, out, out, M, 256, 256, 1.f, 0);
  ln_kernel<<<32768, 256, 0, stream>>>(out, g4, be4, xn);
  gemm_bt<2><<<dim3(4, 1024), 256, 0, stream>>>(xn, c1t, m2b1, nullptr, qkvb, M, 512, 256, 1.f, 0);
  gemm_bt<1><<<dim3(2, 1024), 256, 0, stream>>>(qkvb, c2t, m2b2, out, out, M, 256, 512, 1.f, 0);
}